// Round 1
// baseline (6353.409 us; speedup 1.0000x reference)
//
#include <hip/hip_runtime.h>
#include <hip/hip_bf16.h>
#include <math.h>

// Problem constants
#define B_ 8
#define Q_ 64
#define S_ 48
#define T_ 128
#define H_ 768
#define NH_ 12
#define HD_ 64
#define FF_ 3072

__device__ __forceinline__ float ldA(const float* p, size_t i) { return p[i]; }
__device__ __forceinline__ float ldA(const __hip_bfloat16* p, size_t i) { return __bfloat162float(p[i]); }
__device__ __forceinline__ void stO(float* p, size_t i, float v) { p[i] = v; }
__device__ __forceinline__ void stO(__hip_bfloat16* p, size_t i, float v) { p[i] = __float2bfloat16(v); }

__device__ __forceinline__ float gelu_f(float x) {
  return 0.5f * x * (1.0f + erff(x * 0.70710678118654752f));
}

// ---------------------------------------------------------------------------
// Generic LDS-tiled GEMM: C[M,N] = act(A[M,K] @ W[K,N] + bias)
// 64x64 tile, BK=16, 256 threads, 4x4 microtile per thread.
// M % 64 == 0, N % 64 == 0, K % 16 == 0 guaranteed by problem sizes.
// ---------------------------------------------------------------------------
template<typename AT, typename OT, bool BIAS, bool GELU>
__global__ __launch_bounds__(256) void gemm64(
    const AT* __restrict__ A, const float* __restrict__ W,
    const float* __restrict__ bias, OT* __restrict__ C,
    int M, int N, int K)
{
  __shared__ float As[16][65];   // [kk][m]
  __shared__ float Ws[16][65];   // [kk][n]
  const int tid = threadIdx.x;
  const int m0 = blockIdx.y * 64;
  const int n0 = blockIdx.x * 64;
  const int tx = (tid & 15) * 4;
  const int ty = (tid >> 4) * 4;
  float acc[4][4] = {};

  for (int k0 = 0; k0 < K; k0 += 16) {
    #pragma unroll
    for (int r = 0; r < 4; ++r) {
      int idx = tid + r * 256;           // 0..1023 over 64m x 16k
      int mm = idx >> 4, kk = idx & 15;
      As[kk][mm] = ldA(A, (size_t)(m0 + mm) * K + (k0 + kk));
    }
    #pragma unroll
    for (int r = 0; r < 4; ++r) {
      int idx = tid + r * 256;           // 0..1023 over 16k x 64n
      int kk = idx >> 6, nn = idx & 63;
      Ws[kk][nn] = W[(size_t)(k0 + kk) * N + (n0 + nn)];
    }
    __syncthreads();
    #pragma unroll
    for (int kk = 0; kk < 16; ++kk) {
      float a[4], b[4];
      #pragma unroll
      for (int i = 0; i < 4; ++i) a[i] = As[kk][ty + i];
      #pragma unroll
      for (int j = 0; j < 4; ++j) b[j] = Ws[kk][tx + j];
      #pragma unroll
      for (int i = 0; i < 4; ++i)
        #pragma unroll
        for (int j = 0; j < 4; ++j) acc[i][j] += a[i] * b[j];
    }
    __syncthreads();
  }

  #pragma unroll
  for (int i = 0; i < 4; ++i) {
    int mm = m0 + ty + i;
    #pragma unroll
    for (int j = 0; j < 4; ++j) {
      int nn = n0 + tx + j;
      float v = acc[i][j];
      if (BIAS) v += bias[nn];
      if (GELU) v = gelu_f(v);
      stO(C, (size_t)mm * N + nn, v);
    }
  }
}

// ---------------------------------------------------------------------------
// Fused attention for one (b, h, s, q-half): scores -> softmax(t) -> PV.
// Block handles 32 q-rows x 128 t x 64 d. All in LDS (58.6 KB).
// res[b,q,s,h*64+d] written to d_out (used as scratch).
// ---------------------------------------------------------------------------
__global__ __launch_bounds__(256) void attn_kernel(
    const float* __restrict__ qp, const __hip_bfloat16* __restrict__ kvp,
    const int* __restrict__ mask, float* __restrict__ res)
{
  const int s = blockIdx.x;        // 0..47
  const int h = blockIdx.y;        // 0..11
  const int bz = blockIdx.z;       // 0..15
  const int b = bz >> 1;
  const int qh = (bz & 1) * 32;    // q offset within 64

  __shared__ float Qs[32][65];     // [q][d]
  __shared__ float Ks[128][65];    // [t][d]
  __shared__ float Sc[32][129];    // [q][t]
  __shared__ float mv[128];

  const int tid = threadIdx.x;

  if (tid < 128) mv[tid] = (float)mask[((size_t)b * S_ + s) * T_ + tid] * -10000.0f;

  // load Q tile 32x64 (fp32)
  #pragma unroll
  for (int r = 0; r < 8; ++r) {
    int idx = tid + r * 256;
    int qq = idx >> 6, d = idx & 63;
    Qs[qq][d] = qp[(size_t)(b * Q_ + qh + qq) * H_ + h * HD_ + d];
  }
  // load K/V tile 128x64 (bf16 -> fp32)
  const __hip_bfloat16* kb = kvp + ((size_t)(b * S_ + s) * T_) * H_ + h * HD_;
  #pragma unroll
  for (int r = 0; r < 32; ++r) {
    int idx = tid + r * 256;
    int t = idx >> 6, d = idx & 63;
    Ks[t][d] = __bfloat162float(kb[(size_t)t * H_ + d]);
  }
  __syncthreads();

  // scores: 32q x 128t over K=64. thread = (tq 8 groups of 4 rows) x (tt 32 groups of 4 cols)
  {
    const int tq = (tid >> 5) * 4;
    const int tt = (tid & 31) * 4;
    float acc[4][4] = {};
    for (int d = 0; d < 64; ++d) {
      float a[4], bb[4];
      #pragma unroll
      for (int i = 0; i < 4; ++i) a[i] = Qs[tq + i][d];
      #pragma unroll
      for (int j = 0; j < 4; ++j) bb[j] = Ks[tt + j][d];
      #pragma unroll
      for (int i = 0; i < 4; ++i)
        #pragma unroll
        for (int j = 0; j < 4; ++j) acc[i][j] += a[i] * bb[j];
    }
    #pragma unroll
    for (int i = 0; i < 4; ++i)
      #pragma unroll
      for (int j = 0; j < 4; ++j)
        Sc[tq + i][tt + j] = acc[i][j] * 0.125f + mv[tt + j];
  }
  __syncthreads();

  // softmax over t per q-row (rows 0..31 handled by lanes 0..31)
  if (tid < 32) {
    float mx = -1e30f;
    for (int t = 0; t < 128; ++t) mx = fmaxf(mx, Sc[tid][t]);
    float sum = 0.0f;
    for (int t = 0; t < 128; ++t) {
      float e = expf(Sc[tid][t] - mx);
      Sc[tid][t] = e;
      sum += e;
    }
    float inv = 1.0f / sum;
    for (int t = 0; t < 128; ++t) Sc[tid][t] *= inv;
  }
  __syncthreads();

  // PV: out[32q][64d] over K=128. thread = (16 groups of 2 rows) x (16 groups of 4 cols)
  {
    const int tq = (tid >> 4) * 2;
    const int td = (tid & 15) * 4;
    float o[2][4] = {};
    for (int t = 0; t < 128; ++t) {
      float a0 = Sc[tq][t], a1 = Sc[tq + 1][t];
      float bb[4];
      #pragma unroll
      for (int j = 0; j < 4; ++j) bb[j] = Ks[t][td + j];
      #pragma unroll
      for (int j = 0; j < 4; ++j) { o[0][j] += a0 * bb[j]; o[1][j] += a1 * bb[j]; }
    }
    #pragma unroll
    for (int i = 0; i < 2; ++i) {
      int q = qh + tq + i;
      float* dst = res + ((size_t)(b * Q_ + q) * S_ + s) * H_ + h * HD_ + td;
      #pragma unroll
      for (int j = 0; j < 4; ++j) dst[j] = o[i][j];
    }
  }
}

// ---------------------------------------------------------------------------
// Row LayerNorm over H=768. Block (256 thr) per row, 3 elements per thread.
// ADD: x = X[row] + X2[row] first (final residual+LN).
// ---------------------------------------------------------------------------
template<bool ADD>
__global__ __launch_bounds__(256) void ln_kernel(
    const float* __restrict__ X, const float* __restrict__ X2,
    const float* __restrict__ g, const float* __restrict__ bta,
    float* __restrict__ Y)
{
  const size_t row = blockIdx.x;
  const int tid = threadIdx.x;
  const float* x = X + row * H_;
  float v[3];
  #pragma unroll
  for (int i = 0; i < 3; ++i) {
    int c = tid + i * 256;
    v[i] = x[c];
    if (ADD) v[i] += X2[row * H_ + c];
  }
  float sum = v[0] + v[1] + v[2];
  #pragma unroll
  for (int off = 32; off > 0; off >>= 1) sum += __shfl_down(sum, off, 64);
  __shared__ float red[8];
  const int w = tid >> 6;
  if ((tid & 63) == 0) red[w] = sum;
  __syncthreads();
  const float mean = (red[0] + red[1] + red[2] + red[3]) * (1.0f / 768.0f);
  float vs = 0.0f;
  #pragma unroll
  for (int i = 0; i < 3; ++i) { v[i] -= mean; vs += v[i] * v[i]; }
  #pragma unroll
  for (int off = 32; off > 0; off >>= 1) vs += __shfl_down(vs, off, 64);
  if ((tid & 63) == 0) red[4 + w] = vs;
  __syncthreads();
  const float rstd = rsqrtf((red[4] + red[5] + red[6] + red[7]) * (1.0f / 768.0f) + 1e-12f);
  float* y = Y + row * H_;
  #pragma unroll
  for (int i = 0; i < 3; ++i) {
    int c = tid + i * 256;
    y[c] = v[i] * rstd * g[c] + bta[c];
  }
}

// ---------------------------------------------------------------------------
extern "C" void kernel_launch(void* const* d_in, const int* in_sizes, int n_in,
                              void* d_out, int out_size, void* d_ws, size_t ws_size,
                              hipStream_t stream) {
  const float* q    = (const float*)d_in[0];
  const float* k    = (const float*)d_in[1];
  const int*   mask = (const int*)d_in[2];
  const float* Wq   = (const float*)d_in[3];
  const float* Wkv  = (const float*)d_in[4];
  const float* Wo   = (const float*)d_in[5];
  const float* bo   = (const float*)d_in[6];
  const float* ln1g = (const float*)d_in[7];
  const float* ln1b = (const float*)d_in[8];
  const float* W1   = (const float*)d_in[9];
  const float* b1   = (const float*)d_in[10];
  const float* W2   = (const float*)d_in[11];
  const float* b2   = (const float*)d_in[12];
  const float* ln2g = (const float*)d_in[13];
  const float* ln2b = (const float*)d_in[14];
  float* out = (float*)d_out;

  const int MROWS = B_ * Q_ * S_;           // 24576
  const int KVROWS = B_ * S_ * T_;          // 49152

  // workspace layout
  float* qp = (float*)d_ws;                                   // 512*768 f32
  __hip_bfloat16* kvp = (__hip_bfloat16*)(qp + 512 * H_);     // 49152*768 bf16
  float* attn = (float*)(kvp + (size_t)KVROWS * H_);          // 24576*768 f32
  float* ffn2 = attn + (size_t)MROWS * H_;                    // 24576*768 f32
  __hip_bfloat16* ffn1 = (__hip_bfloat16*)(ffn2 + (size_t)MROWS * H_); // 24576*3072 bf16

  dim3 blk(256);

  // 1. q projection: [512,768] @ [768,768]
  gemm64<float, float, false, false>
      <<<dim3(H_ / 64, 512 / 64), blk, 0, stream>>>(q, Wq, nullptr, qp, 512, H_, H_);
  // 2. kv projection: [49152,768] @ [768,768] -> bf16
  gemm64<float, __hip_bfloat16, false, false>
      <<<dim3(H_ / 64, KVROWS / 64), blk, 0, stream>>>(k, Wkv, nullptr, kvp, KVROWS, H_, H_);
  // 3. attention -> res (stored in d_out as scratch)
  attn_kernel<<<dim3(S_, NH_, B_ * 2), blk, 0, stream>>>(qp, kvp, mask, out);
  // 4. res @ Wo + bo -> attn(pre-LN)
  gemm64<float, float, true, false>
      <<<dim3(H_ / 64, MROWS / 64), blk, 0, stream>>>(out, Wo, bo, attn, MROWS, H_, H_);
  // 5. LN1 in-place
  ln_kernel<false><<<MROWS, blk, 0, stream>>>(attn, nullptr, ln1g, ln1b, attn);
  // 6. attn @ W1 + b1, gelu -> ffn1 (bf16)
  gemm64<float, __hip_bfloat16, true, true>
      <<<dim3(FF_ / 64, MROWS / 64), blk, 0, stream>>>(attn, W1, b1, ffn1, MROWS, FF_, H_);
  // 7. ffn1 @ W2 + b2 -> ffn2
  gemm64<__hip_bfloat16, float, true, false>
      <<<dim3(H_ / 64, MROWS / 64), blk, 0, stream>>>(ffn1, W2, b2, ffn2, MROWS, H_, FF_);
  // 8. LN2: out = LN(attn + ffn2)
  ln_kernel<true><<<MROWS, blk, 0, stream>>>(attn, ffn2, ln2g, ln2b, out);
}

// Round 3
// 1048.097 us; speedup vs baseline: 6.0618x; 6.0618x over previous
//
#include <hip/hip_runtime.h>
#include <hip/hip_bf16.h>
#include <math.h>

// Problem constants
#define B_ 8
#define Q_ 64
#define S_ 48
#define T_ 128
#define H_ 768
#define NH_ 12
#define HD_ 64
#define FF_ 3072

typedef float f32x4 __attribute__((ext_vector_type(4)));
typedef short s16x8 __attribute__((ext_vector_type(8)));

__device__ __forceinline__ float ldT(const float* p, size_t i) { return p[i]; }
__device__ __forceinline__ float ldT(const __hip_bfloat16* p, size_t i) { return __bfloat162float(p[i]); }
__device__ __forceinline__ void stT(float* p, size_t i, float v) { p[i] = v; }
__device__ __forceinline__ void stT(__hip_bfloat16* p, size_t i, float v) { p[i] = __float2bfloat16(v); }

__device__ __forceinline__ float gelu_f(float x) {
  return 0.5f * x * (1.0f + erff(x * 0.70710678118654752f));
}

// async global->LDS, 16B per lane
__device__ __forceinline__ void gld_lds16(const void* g, void* l) {
  __builtin_amdgcn_global_load_lds(
      (const __attribute__((address_space(1))) void*)g,
      (__attribute__((address_space(3))) void*)l, 16, 0, 0);
}

// ---------------------------------------------------------------------------
// MFMA bf16 GEMM: C[M,N] = act(A[M,K] @ BT[N,K]^T + bias)
// 128x128 tile, BK=32, 256 threads (4 waves, 2x2), each wave 64x64 out.
// LDS: double-buffered A-tile[128][32] + B-tile[128][32] bf16, slot-swizzled.
// Requires M%128==0, N%128==0, K%32==0, grid = (M/128)*(N/128), %8==0.
// ---------------------------------------------------------------------------
__device__ __forceinline__ int swz_off(int row, int kc) {
  // byte offset of 16B chunk (row, k-chunk kc) in a [128][32] bf16 tile,
  // slot swizzled: slot = kc ^ ((row>>1)&3)  (involution)
  return row * 64 + ((kc ^ ((row >> 1) & 3)) << 4);
}

template<typename OT, bool BIAS, bool GELU>
__global__ __launch_bounds__(256) void gemm_mfma(
    const __hip_bfloat16* __restrict__ A,   // [M,K]
    const __hip_bfloat16* __restrict__ BT,  // [N,K]
    const float* __restrict__ bias, OT* __restrict__ C,
    int N, int K, int nbx)
{
  __shared__ char sm[2][16384];   // per buf: A at 0 (8KB), B at 8192 (8KB)

  // XCD-aware chunked swizzle (grid %8 == 0 for all our launches)
  int wg = blockIdx.x;
  const int q8 = gridDim.x >> 3;
  wg = (wg & 7) * q8 + (wg >> 3);
  const int bm = wg / nbx;
  const int bn = wg % nbx;
  const int m0 = bm * 128, n0 = bn * 128;

  const int tid = threadIdx.x;
  const int lane = tid & 63;
  const int wid = tid >> 6;
  const int wr = wid >> 1, wc = wid & 1;

  const int nt = K >> 5;

  auto stage = [&](int buf, int kt) {
    const int k0 = kt << 5;
    const __hip_bfloat16* Ab = A + (size_t)m0 * K + k0;
    const __hip_bfloat16* Bb = BT + (size_t)n0 * K + k0;
    char* smA = sm[buf];
    char* smB = sm[buf] + 8192;
    #pragma unroll
    for (int r = 0; r < 2; ++r) {
      const int c = tid + r * 256;           // chunk 0..511
      const int row = c >> 2, slot = c & 3;
      const int kc = slot ^ ((row >> 1) & 3); // pre-swizzled source
      gld_lds16(Ab + (size_t)row * K + kc * 8, smA + c * 16);
      gld_lds16(Bb + (size_t)row * K + kc * 8, smB + c * 16);
    }
  };

  f32x4 acc[4][4] = {};
  stage(0, 0);

  for (int kt = 0; kt < nt; ++kt) {
    __syncthreads();                         // drains vmcnt -> buf[kt&1] ready
    if (kt + 1 < nt) stage((kt + 1) & 1, kt + 1);
    const char* smA = sm[kt & 1];
    const char* smB = sm[kt & 1] + 8192;
    const int kc = lane >> 4, rl = lane & 15;
    s16x8 af[4], bf[4];
    #pragma unroll
    for (int m = 0; m < 4; ++m)
      af[m] = *(const s16x8*)(smA + swz_off(wr * 64 + m * 16 + rl, kc));
    #pragma unroll
    for (int n = 0; n < 4; ++n)
      bf[n] = *(const s16x8*)(smB + swz_off(wc * 64 + n * 16 + rl, kc));
    #pragma unroll
    for (int m = 0; m < 4; ++m)
      #pragma unroll
      for (int n = 0; n < 4; ++n)
        acc[m][n] = __builtin_amdgcn_mfma_f32_16x16x32_bf16(af[m], bf[n], acc[m][n], 0, 0, 0);
  }

  // epilogue: C/D layout col=lane&15, row=(lane>>4)*4+r  [m89-verified]
  const int colb = n0 + wc * 64 + (lane & 15);
  const int rowb = m0 + wr * 64 + (lane >> 4) * 4;
  #pragma unroll
  for (int n = 0; n < 4; ++n) {
    const int col = colb + n * 16;
    const float bv = BIAS ? bias[col] : 0.0f;
    #pragma unroll
    for (int m = 0; m < 4; ++m) {
      #pragma unroll
      for (int r = 0; r < 4; ++r) {
        const int row = rowb + m * 16 + r;
        float v = acc[m][n][r] + bv;
        if (GELU) v = gelu_f(v);
        stT(C, (size_t)row * N + col, v);
      }
    }
  }
}

// ---------------------------------------------------------------------------
// fp32 LDS-tiled GEMM (kept for tiny q-projection only)
// ---------------------------------------------------------------------------
__global__ __launch_bounds__(256) void gemm64(
    const float* __restrict__ A, const float* __restrict__ W,
    float* __restrict__ C, int M, int N, int K)
{
  __shared__ float As[16][65];
  __shared__ float Ws[16][65];
  const int tid = threadIdx.x;
  const int m0 = blockIdx.y * 64;
  const int n0 = blockIdx.x * 64;
  const int tx = (tid & 15) * 4;
  const int ty = (tid >> 4) * 4;
  float acc[4][4] = {};

  for (int k0 = 0; k0 < K; k0 += 16) {
    #pragma unroll
    for (int r = 0; r < 4; ++r) {
      int idx = tid + r * 256;
      int mm = idx >> 4, kk = idx & 15;
      As[kk][mm] = A[(size_t)(m0 + mm) * K + (k0 + kk)];
    }
    #pragma unroll
    for (int r = 0; r < 4; ++r) {
      int idx = tid + r * 256;
      int kk = idx >> 6, nn = idx & 63;
      Ws[kk][nn] = W[(size_t)(k0 + kk) * N + (n0 + nn)];
    }
    __syncthreads();
    #pragma unroll
    for (int kk = 0; kk < 16; ++kk) {
      float a[4], b[4];
      #pragma unroll
      for (int i = 0; i < 4; ++i) a[i] = As[kk][ty + i];
      #pragma unroll
      for (int j = 0; j < 4; ++j) b[j] = Ws[kk][tx + j];
      #pragma unroll
      for (int i = 0; i < 4; ++i)
        #pragma unroll
        for (int j = 0; j < 4; ++j) acc[i][j] += a[i] * b[j];
    }
    __syncthreads();
  }
  #pragma unroll
  for (int i = 0; i < 4; ++i)
    #pragma unroll
    for (int j = 0; j < 4; ++j)
      C[(size_t)(m0 + ty + i) * N + (n0 + tx + j)] = acc[i][j];
}

// ---------------------------------------------------------------------------
// weight transpose-cast: W[K,N] f32 -> WT[N,K] bf16
// ---------------------------------------------------------------------------
__global__ __launch_bounds__(256) void transpose_cast(
    const float* __restrict__ W, __hip_bfloat16* __restrict__ WT, int K, int N)
{
  __shared__ float t[32][33];
  const int n0 = blockIdx.x * 32, k0 = blockIdx.y * 32;
  const int x = threadIdx.x & 31, y4 = (threadIdx.x >> 5) * 4;
  #pragma unroll
  for (int i = 0; i < 4; ++i)
    t[y4 + i][x] = W[(size_t)(k0 + y4 + i) * N + n0 + x];
  __syncthreads();
  #pragma unroll
  for (int i = 0; i < 4; ++i)
    WT[(size_t)(n0 + y4 + i) * K + k0 + x] = __float2bfloat16(t[x][y4 + i]);
}

// elementwise cast f32 -> bf16, 4 elems/thread
__global__ __launch_bounds__(256) void cast_f32_bf16(
    const float* __restrict__ x, __hip_bfloat16* __restrict__ y, size_t n4)
{
  const size_t i = (size_t)blockIdx.x * 256 + threadIdx.x;
  if (i >= n4) return;
  const float4 v = ((const float4*)x)[i];
  __hip_bfloat16 o[4] = { __float2bfloat16(v.x), __float2bfloat16(v.y),
                          __float2bfloat16(v.z), __float2bfloat16(v.w) };
  *(ushort4*)(y + i * 4) = *(ushort4*)o;
}

// ---------------------------------------------------------------------------
// Fused attention for one (b, h, s, q-half). Scores -> softmax(t) -> PV.
// ---------------------------------------------------------------------------
__global__ __launch_bounds__(256) void attn_kernel(
    const float* __restrict__ qp, const __hip_bfloat16* __restrict__ kvp,
    const int* __restrict__ mask, __hip_bfloat16* __restrict__ res)
{
  const int s = blockIdx.x;
  const int h = blockIdx.y;
  const int bz = blockIdx.z;
  const int b = bz >> 1;
  const int qh = (bz & 1) * 32;

  __shared__ float Qs[32][65];
  __shared__ float Ks[128][65];
  __shared__ float Sc[32][129];
  __shared__ float mv[128];

  const int tid = threadIdx.x;

  if (tid < 128) mv[tid] = (float)mask[((size_t)b * S_ + s) * T_ + tid] * -10000.0f;

  #pragma unroll
  for (int r = 0; r < 8; ++r) {
    int idx = tid + r * 256;
    int qq = idx >> 6, d = idx & 63;
    Qs[qq][d] = qp[(size_t)(b * Q_ + qh + qq) * H_ + h * HD_ + d];
  }
  const __hip_bfloat16* kb = kvp + ((size_t)(b * S_ + s) * T_) * H_ + h * HD_;
  #pragma unroll
  for (int r = 0; r < 32; ++r) {
    int idx = tid + r * 256;
    int t = idx >> 6, d = idx & 63;
    Ks[t][d] = __bfloat162float(kb[(size_t)t * H_ + d]);
  }
  __syncthreads();

  {
    const int tq = (tid >> 5) * 4;
    const int tt = (tid & 31) * 4;
    float acc[4][4] = {};
    for (int d = 0; d < 64; ++d) {
      float a[4], bb[4];
      #pragma unroll
      for (int i = 0; i < 4; ++i) a[i] = Qs[tq + i][d];
      #pragma unroll
      for (int j = 0; j < 4; ++j) bb[j] = Ks[tt + j][d];
      #pragma unroll
      for (int i = 0; i < 4; ++i)
        #pragma unroll
        for (int j = 0; j < 4; ++j) acc[i][j] += a[i] * bb[j];
    }
    #pragma unroll
    for (int i = 0; i < 4; ++i)
      #pragma unroll
      for (int j = 0; j < 4; ++j)
        Sc[tq + i][tt + j] = acc[i][j] * 0.125f + mv[tt + j];
  }
  __syncthreads();

  if (tid < 32) {
    float mx = -1e30f;
    for (int t = 0; t < 128; ++t) mx = fmaxf(mx, Sc[tid][t]);
    float sum = 0.0f;
    for (int t = 0; t < 128; ++t) {
      float e = expf(Sc[tid][t] - mx);
      Sc[tid][t] = e;
      sum += e;
    }
    float inv = 1.0f / sum;
    for (int t = 0; t < 128; ++t) Sc[tid][t] *= inv;
  }
  __syncthreads();

  {
    const int tq = (tid >> 4) * 2;
    const int td = (tid & 15) * 4;
    float o[2][4] = {};
    for (int t = 0; t < 128; ++t) {
      float a0 = Sc[tq][t], a1 = Sc[tq + 1][t];
      float bb[4];
      #pragma unroll
      for (int j = 0; j < 4; ++j) bb[j] = Ks[t][td + j];
      #pragma unroll
      for (int j = 0; j < 4; ++j) { o[0][j] += a0 * bb[j]; o[1][j] += a1 * bb[j]; }
    }
    #pragma unroll
    for (int i = 0; i < 2; ++i) {
      int q = qh + tq + i;
      __hip_bfloat16* dst = res + ((size_t)(b * Q_ + q) * S_ + s) * H_ + h * HD_ + td;
      #pragma unroll
      for (int j = 0; j < 4; ++j) dst[j] = __float2bfloat16(o[i][j]);
    }
  }
}

// ---------------------------------------------------------------------------
// Row LayerNorm over H=768, templated in/out dtypes.
// ---------------------------------------------------------------------------
template<bool ADD, typename IT, typename OT>
__global__ __launch_bounds__(256) void ln_kernel(
    const IT* __restrict__ X, const IT* __restrict__ X2,
    const float* __restrict__ g, const float* __restrict__ bta,
    OT* __restrict__ Y)
{
  const size_t row = blockIdx.x;
  const int tid = threadIdx.x;
  float v[3];
  #pragma unroll
  for (int i = 0; i < 3; ++i) {
    int c = tid + i * 256;
    v[i] = ldT(X, row * H_ + c);
    if (ADD) v[i] += ldT(X2, row * H_ + c);
  }
  float sum = v[0] + v[1] + v[2];
  #pragma unroll
  for (int off = 32; off > 0; off >>= 1) sum += __shfl_down(sum, off, 64);
  __shared__ float red[8];
  const int w = tid >> 6;
  if ((tid & 63) == 0) red[w] = sum;
  __syncthreads();
  const float mean = (red[0] + red[1] + red[2] + red[3]) * (1.0f / 768.0f);
  float vs = 0.0f;
  #pragma unroll
  for (int i = 0; i < 3; ++i) { v[i] -= mean; vs += v[i] * v[i]; }
  #pragma unroll
  for (int off = 32; off > 0; off >>= 1) vs += __shfl_down(vs, off, 64);
  if ((tid & 63) == 0) red[4 + w] = vs;
  __syncthreads();
  const float rstd = rsqrtf((red[4] + red[5] + red[6] + red[7]) * (1.0f / 768.0f) + 1e-12f);
  #pragma unroll
  for (int i = 0; i < 3; ++i) {
    int c = tid + i * 256;
    stT(Y, row * H_ + c, v[i] * rstd * g[c] + bta[c]);
  }
}

// ---------------------------------------------------------------------------
extern "C" void kernel_launch(void* const* d_in, const int* in_sizes, int n_in,
                              void* d_out, int out_size, void* d_ws, size_t ws_size,
                              hipStream_t stream) {
  const float* q    = (const float*)d_in[0];
  const float* k    = (const float*)d_in[1];
  const int*   mask = (const int*)d_in[2];
  const float* Wq   = (const float*)d_in[3];
  const float* Wkv  = (const float*)d_in[4];
  const float* Wo   = (const float*)d_in[5];
  const float* bo   = (const float*)d_in[6];
  const float* ln1g = (const float*)d_in[7];
  const float* ln1b = (const float*)d_in[8];
  const float* W1   = (const float*)d_in[9];
  const float* b1   = (const float*)d_in[10];
  const float* W2   = (const float*)d_in[11];
  const float* b2   = (const float*)d_in[12];
  const float* ln2g = (const float*)d_in[13];
  const float* ln2b = (const float*)d_in[14];
  float* out = (float*)d_out;

  const int MROWS = B_ * Q_ * S_;           // 24576
  const int KVROWS = B_ * S_ * T_;          // 49152

  // workspace layout (bytes), with lifetime-based reuse:
  char* ws = (char*)d_ws;
  __hip_bfloat16* kbf  = (__hip_bfloat16*)ws;                        // 75.5MB [dead after kv gemm]
  __hip_bfloat16* kvp  = (__hip_bfloat16*)(ws + 75497472);           // 75.5MB [dead after attn]
  __hip_bfloat16* ffn1 = (__hip_bfloat16*)ws;                        // 151MB, reuses kbf+kvp
  __hip_bfloat16* ares = (__hip_bfloat16*)(ws + 150994944);          // 37.7MB [dead after Wo gemm]
  __hip_bfloat16* ffn2 = ares;                                       // reuse
  __hip_bfloat16* aln  = (__hip_bfloat16*)(ws + 188743680);          // 37.7MB
  float*          qp   = (float*)(ws + 226492416);                   // 1.6MB
  __hip_bfloat16* WkvT = (__hip_bfloat16*)(ws + 228065280);
  __hip_bfloat16* WoT  = (__hip_bfloat16*)(ws + 229244928);
  __hip_bfloat16* W1T  = (__hip_bfloat16*)(ws + 230424576);
  __hip_bfloat16* W2T  = (__hip_bfloat16*)(ws + 235143168);

  dim3 blk(256);

  // weight prep
  transpose_cast<<<dim3(24, 24), blk, 0, stream>>>(Wkv, WkvT, H_, H_);
  transpose_cast<<<dim3(24, 24), blk, 0, stream>>>(Wo, WoT, H_, H_);
  transpose_cast<<<dim3(96, 24), blk, 0, stream>>>(W1, W1T, H_, FF_);
  transpose_cast<<<dim3(24, 96), blk, 0, stream>>>(W2, W2T, FF_, H_);
  // k -> bf16
  cast_f32_bf16<<<dim3((KVROWS * H_ / 4 + 255) / 256), blk, 0, stream>>>(
      k, kbf, (size_t)KVROWS * H_ / 4);

  // 1. q projection (fp32, tiny)
  gemm64<<<dim3(H_ / 64, 512 / 64), blk, 0, stream>>>(q, Wq, qp, 512, H_, H_);
  // 2. kv projection: [49152,768]x[768,768] -> bf16
  gemm_mfma<__hip_bfloat16, false, false>
      <<<dim3((KVROWS / 128) * (H_ / 128)), blk, 0, stream>>>(
      kbf, WkvT, nullptr, kvp, H_, H_, H_ / 128);
  // 3. attention -> ares (bf16)
  attn_kernel<<<dim3(S_, NH_, B_ * 2), blk, 0, stream>>>(qp, kvp, mask, ares);
  // 4. ares @ Wo + bo -> d_out (f32, pre-LN scratch)
  gemm_mfma<float, true, false>
      <<<dim3((MROWS / 128) * (H_ / 128)), blk, 0, stream>>>(
      ares, WoT, bo, out, H_, H_, H_ / 128);
  // 5. LN1: d_out -> aln (bf16)
  ln_kernel<false, float, __hip_bfloat16><<<MROWS, blk, 0, stream>>>(
      out, nullptr, ln1g, ln1b, aln);
  // 6. aln @ W1 + b1, gelu -> ffn1 (bf16)
  gemm_mfma<__hip_bfloat16, true, true>
      <<<dim3((MROWS / 128) * (FF_ / 128)), blk, 0, stream>>>(
      aln, W1T, b1, ffn1, FF_, H_, FF_ / 128);
  // 7. ffn1 @ W2 + b2 -> ffn2 (bf16)
  gemm_mfma<__hip_bfloat16, true, false>
      <<<dim3((MROWS / 128) * (H_ / 128)), blk, 0, stream>>>(
      ffn1, W2T, b2, ffn2, H_, FF_, H_ / 128);
  // 8. LN2: out = LN(aln + ffn2)
  ln_kernel<true, __hip_bfloat16, float><<<MROWS, blk, 0, stream>>>(
      aln, ffn2, ln2g, ln2b, out);
}

// Round 4
// 684.161 us; speedup vs baseline: 9.2864x; 1.5319x over previous
//
#include <hip/hip_runtime.h>
#include <hip/hip_bf16.h>
#include <math.h>

// Problem constants
#define B_ 8
#define Q_ 64
#define S_ 48
#define T_ 128
#define H_ 768
#define NH_ 12
#define HD_ 64
#define FF_ 3072

typedef float f32x4 __attribute__((ext_vector_type(4)));
typedef short s16x8 __attribute__((ext_vector_type(8)));
typedef short s16x4 __attribute__((ext_vector_type(4)));

__device__ __forceinline__ float ldT(const float* p, size_t i) { return p[i]; }
__device__ __forceinline__ float ldT(const __hip_bfloat16* p, size_t i) { return __bfloat162float(p[i]); }
__device__ __forceinline__ void stT(float* p, size_t i, float v) { p[i] = v; }
__device__ __forceinline__ void stT(__hip_bfloat16* p, size_t i, float v) { p[i] = __float2bfloat16(v); }

__device__ __forceinline__ short f2bf(float f) {
  __hip_bfloat16 h = __float2bfloat16(f);
  return *reinterpret_cast<short*>(&h);
}

__device__ __forceinline__ float gelu_f(float x) {
  return 0.5f * x * (1.0f + erff(x * 0.70710678118654752f));
}

// async global->LDS, 16B per lane
__device__ __forceinline__ void gld_lds16(const void* g, void* l) {
  __builtin_amdgcn_global_load_lds(
      (const __attribute__((address_space(1))) void*)g,
      (__attribute__((address_space(3))) void*)l, 16, 0, 0);
}

// ---------------------------------------------------------------------------
// MFMA bf16 GEMM: C[M,N] = act(A[M,K] @ BT[N,K]^T + bias)  (unchanged, R3)
// ---------------------------------------------------------------------------
__device__ __forceinline__ int swz_off(int row, int kc) {
  return row * 64 + ((kc ^ ((row >> 1) & 3)) << 4);
}

template<typename OT, bool BIAS, bool GELU>
__global__ __launch_bounds__(256) void gemm_mfma(
    const __hip_bfloat16* __restrict__ A,   // [M,K]
    const __hip_bfloat16* __restrict__ BT,  // [N,K]
    const float* __restrict__ bias, OT* __restrict__ C,
    int N, int K, int nbx)
{
  __shared__ char sm[2][16384];

  int wg = blockIdx.x;
  const int q8 = gridDim.x >> 3;
  wg = (wg & 7) * q8 + (wg >> 3);
  const int bm = wg / nbx;
  const int bn = wg % nbx;
  const int m0 = bm * 128, n0 = bn * 128;

  const int tid = threadIdx.x;
  const int lane = tid & 63;
  const int wid = tid >> 6;
  const int wr = wid >> 1, wc = wid & 1;

  const int nt = K >> 5;

  auto stage = [&](int buf, int kt) {
    const int k0 = kt << 5;
    const __hip_bfloat16* Ab = A + (size_t)m0 * K + k0;
    const __hip_bfloat16* Bb = BT + (size_t)n0 * K + k0;
    char* smA = sm[buf];
    char* smB = sm[buf] + 8192;
    #pragma unroll
    for (int r = 0; r < 2; ++r) {
      const int c = tid + r * 256;
      const int row = c >> 2, slot = c & 3;
      const int kc = slot ^ ((row >> 1) & 3);
      gld_lds16(Ab + (size_t)row * K + kc * 8, smA + c * 16);
      gld_lds16(Bb + (size_t)row * K + kc * 8, smB + c * 16);
    }
  };

  f32x4 acc[4][4] = {};
  stage(0, 0);

  for (int kt = 0; kt < nt; ++kt) {
    __syncthreads();
    if (kt + 1 < nt) stage((kt + 1) & 1, kt + 1);
    const char* smA = sm[kt & 1];
    const char* smB = sm[kt & 1] + 8192;
    const int kc = lane >> 4, rl = lane & 15;
    s16x8 af[4], bf[4];
    #pragma unroll
    for (int m = 0; m < 4; ++m)
      af[m] = *(const s16x8*)(smA + swz_off(wr * 64 + m * 16 + rl, kc));
    #pragma unroll
    for (int n = 0; n < 4; ++n)
      bf[n] = *(const s16x8*)(smB + swz_off(wc * 64 + n * 16 + rl, kc));
    #pragma unroll
    for (int m = 0; m < 4; ++m)
      #pragma unroll
      for (int n = 0; n < 4; ++n)
        acc[m][n] = __builtin_amdgcn_mfma_f32_16x16x32_bf16(af[m], bf[n], acc[m][n], 0, 0, 0);
  }

  const int colb = n0 + wc * 64 + (lane & 15);
  const int rowb = m0 + wr * 64 + (lane >> 4) * 4;
  #pragma unroll
  for (int n = 0; n < 4; ++n) {
    const int col = colb + n * 16;
    const float bv = BIAS ? bias[col] : 0.0f;
    #pragma unroll
    for (int m = 0; m < 4; ++m) {
      #pragma unroll
      for (int r = 0; r < 4; ++r) {
        const int row = rowb + m * 16 + r;
        float v = acc[m][n][r] + bv;
        if (GELU) v = gelu_f(v);
        stT(C, (size_t)row * N + col, v);
      }
    }
  }
}

// ---------------------------------------------------------------------------
// fp32 LDS-tiled GEMM (q-projection only), templated output
// ---------------------------------------------------------------------------
template<typename OT>
__global__ __launch_bounds__(256) void gemm64(
    const float* __restrict__ A, const float* __restrict__ W,
    OT* __restrict__ C, int M, int N, int K)
{
  __shared__ float As[16][65];
  __shared__ float Ws[16][65];
  const int tid = threadIdx.x;
  const int m0 = blockIdx.y * 64;
  const int n0 = blockIdx.x * 64;
  const int tx = (tid & 15) * 4;
  const int ty = (tid >> 4) * 4;
  float acc[4][4] = {};

  for (int k0 = 0; k0 < K; k0 += 16) {
    #pragma unroll
    for (int r = 0; r < 4; ++r) {
      int idx = tid + r * 256;
      int mm = idx >> 4, kk = idx & 15;
      As[kk][mm] = A[(size_t)(m0 + mm) * K + (k0 + kk)];
    }
    #pragma unroll
    for (int r = 0; r < 4; ++r) {
      int idx = tid + r * 256;
      int kk = idx >> 6, nn = idx & 63;
      Ws[kk][nn] = W[(size_t)(k0 + kk) * N + (n0 + nn)];
    }
    __syncthreads();
    #pragma unroll
    for (int kk = 0; kk < 16; ++kk) {
      float a[4], b[4];
      #pragma unroll
      for (int i = 0; i < 4; ++i) a[i] = As[kk][ty + i];
      #pragma unroll
      for (int j = 0; j < 4; ++j) b[j] = Ws[kk][tx + j];
      #pragma unroll
      for (int i = 0; i < 4; ++i)
        #pragma unroll
        for (int j = 0; j < 4; ++j) acc[i][j] += a[i] * b[j];
    }
    __syncthreads();
  }
  #pragma unroll
  for (int i = 0; i < 4; ++i)
    #pragma unroll
    for (int j = 0; j < 4; ++j)
      stT(C, (size_t)(m0 + ty + i) * N + (n0 + tx + j), acc[i][j]);
}

// ---------------------------------------------------------------------------
// weight transpose-cast: W[K,N] f32 -> WT[N,K] bf16
// ---------------------------------------------------------------------------
__global__ __launch_bounds__(256) void transpose_cast(
    const float* __restrict__ W, __hip_bfloat16* __restrict__ WT, int K, int N)
{
  __shared__ float t[32][33];
  const int n0 = blockIdx.x * 32, k0 = blockIdx.y * 32;
  const int x = threadIdx.x & 31, y4 = (threadIdx.x >> 5) * 4;
  #pragma unroll
  for (int i = 0; i < 4; ++i)
    t[y4 + i][x] = W[(size_t)(k0 + y4 + i) * N + n0 + x];
  __syncthreads();
  #pragma unroll
  for (int i = 0; i < 4; ++i)
    WT[(size_t)(n0 + y4 + i) * K + k0 + x] = __float2bfloat16(t[x][y4 + i]);
}

// elementwise cast f32 -> bf16, 4 elems/thread
__global__ __launch_bounds__(256) void cast_f32_bf16(
    const float* __restrict__ x, __hip_bfloat16* __restrict__ y, size_t n4)
{
  const size_t i = (size_t)blockIdx.x * 256 + threadIdx.x;
  if (i >= n4) return;
  const float4 v = ((const float4*)x)[i];
  __hip_bfloat16 o[4] = { __float2bfloat16(v.x), __float2bfloat16(v.y),
                          __float2bfloat16(v.z), __float2bfloat16(v.w) };
  *(ushort4*)(y + i * 4) = *(ushort4*)o;
}

// ---------------------------------------------------------------------------
// MFMA attention. Block = (s, h, b). 256 threads = 4 waves (2x2).
// QK^T: 64q x 128t over d=64; softmax over t; PV: 64q x 64d over t=128.
// LDS: Ks 16K | VT 16K | SC 32K (Qs overlay / Sc f32 / Pb bf16) | mv 512B
// All tiles chunk-XOR swizzled for bank-conflict-free ds_read_b128.
// ---------------------------------------------------------------------------
__global__ __launch_bounds__(256) void attn_mfma(
    const __hip_bfloat16* __restrict__ qp,   // [B*Q][H] bf16
    const __hip_bfloat16* __restrict__ kvp,  // [B*S*T][H] bf16
    const int* __restrict__ mask,
    __hip_bfloat16* __restrict__ res)        // [B,Q,S,H] bf16
{
  const int s = blockIdx.x, h = blockIdx.y, b = blockIdx.z;
  __shared__ __align__(16) char lds[66048];
  char* Ks = lds;                  // [128t][64d]: chunk(t,kc8)@ t*128+((kc8^(t&7))<<4)
  char* VT = lds + 16384;          // [64d][128t]: chunk(d,tc)@ d*256+((tc^(d&15))<<4)
  char* SC = lds + 32768;          // Qs overlay; Sc f32 (q,tc32)@ q*512+((tc32^(q&31))<<4)
                                   // Pb bf16 (q,tcp)@ q*512+((tcp^(q&15))<<4)
  float* mv = (float*)(lds + 65536);

  const int tid = threadIdx.x;
  const int lane = tid & 63;
  const int wid = tid >> 6;
  const int wr = wid >> 1, wc = wid & 1;
  const int kcg = lane >> 4, rl = lane & 15;

  if (tid < 128) mv[tid] = (float)mask[((size_t)b * S_ + s) * T_ + tid] * -10000.0f;

  // --- stage Q via global_load_lds (linear LDS dest, pre-swizzled source) ---
  {
    const __hip_bfloat16* qb = qp + ((size_t)b * Q_) * H_ + h * HD_;
    #pragma unroll
    for (int r = 0; r < 2; ++r) {
      const int c = tid + r * 256;            // 512 chunks: Qs[64q][8 chunks]
      const int qq = c >> 3, sc = c & 7;
      const int kc8 = sc ^ (qq & 7);
      gld_lds16(qb + (size_t)qq * H_ + kc8 * 8, SC + c * 16);
    }
  }
  // --- stage K/V via registers: Ks (swizzled b128) + VT (transposed b64) ---
  {
    const int kc8 = tid & 7, tg = tid >> 3;   // tg 0..31, t0 = tg*4
    const int t0 = tg * 4;
    const __hip_bfloat16* kb = kvp + (((size_t)b * S_ + s) * T_) * H_ + h * HD_ + kc8 * 8;
    s16x8 r0 = *(const s16x8*)(kb + (size_t)(t0 + 0) * H_);
    s16x8 r1 = *(const s16x8*)(kb + (size_t)(t0 + 1) * H_);
    s16x8 r2 = *(const s16x8*)(kb + (size_t)(t0 + 2) * H_);
    s16x8 r3 = *(const s16x8*)(kb + (size_t)(t0 + 3) * H_);
    *(s16x8*)(Ks + (t0 + 0) * 128 + ((kc8 ^ ((t0 + 0) & 7)) << 4)) = r0;
    *(s16x8*)(Ks + (t0 + 1) * 128 + ((kc8 ^ ((t0 + 1) & 7)) << 4)) = r1;
    *(s16x8*)(Ks + (t0 + 2) * 128 + ((kc8 ^ ((t0 + 2) & 7)) << 4)) = r2;
    *(s16x8*)(Ks + (t0 + 3) * 128 + ((kc8 ^ ((t0 + 3) & 7)) << 4)) = r3;
    const int tc = tg >> 1;
    const int toff = (tg & 1) * 8;
    #pragma unroll
    for (int j = 0; j < 8; ++j) {
      s16x4 v4 = { r0[j], r1[j], r2[j], r3[j] };
      const int d = kc8 * 8 + j;
      *(s16x4*)(VT + d * 256 + ((tc ^ (d & 15)) << 4) + toff) = v4;
    }
  }
  __syncthreads();

  // --- QK^T ---
  f32x4 acc[2][4] = {};
  {
    s16x8 af[2][2], bf[2][4];
    #pragma unroll
    for (int kk = 0; kk < 2; ++kk) {
      #pragma unroll
      for (int m = 0; m < 2; ++m) {
        const int q = wr * 32 + m * 16 + rl;
        const int kc8 = kk * 4 + kcg;
        af[kk][m] = *(const s16x8*)(SC + q * 128 + ((kc8 ^ (q & 7)) << 4));
      }
      #pragma unroll
      for (int n = 0; n < 4; ++n) {
        const int t = wc * 64 + n * 16 + rl;
        const int kc8 = kk * 4 + kcg;
        bf[kk][n] = *(const s16x8*)(Ks + t * 128 + ((kc8 ^ (t & 7)) << 4));
      }
    }
    #pragma unroll
    for (int kk = 0; kk < 2; ++kk)
      #pragma unroll
      for (int m = 0; m < 2; ++m)
        #pragma unroll
        for (int n = 0; n < 4; ++n)
          acc[m][n] = __builtin_amdgcn_mfma_f32_16x16x32_bf16(af[kk][m], bf[kk][n], acc[m][n], 0, 0, 0);
  }
  __syncthreads();   // all Qs frag reads done before Sc overwrites the region

  // epilogue: Sc = acc*SCALE + mask
  #pragma unroll
  for (int m = 0; m < 2; ++m)
    #pragma unroll
    for (int n = 0; n < 4; ++n)
      #pragma unroll
      for (int r = 0; r < 4; ++r) {
        const int q = wr * 32 + m * 16 + (lane >> 4) * 4 + r;
        const int t = wc * 64 + n * 16 + rl;
        const int tc32 = t >> 2;
        *(float*)(SC + q * 512 + ((tc32 ^ (q & 31)) << 4) + (t & 3) * 4) =
            acc[m][n][r] * 0.125f + mv[t];
      }
  __syncthreads();

  // --- softmax: 4 lanes per q-row, 32 t each ---
  {
    const int q = tid >> 2, quarter = tid & 3;
    float vals[32];
    #pragma unroll
    for (int j = 0; j < 8; ++j) {
      const int tc32 = quarter * 8 + j;
      const f32x4 c = *(const f32x4*)(SC + q * 512 + ((tc32 ^ (q & 31)) << 4));
      vals[j * 4 + 0] = c[0]; vals[j * 4 + 1] = c[1];
      vals[j * 4 + 2] = c[2]; vals[j * 4 + 3] = c[3];
    }
    float mx = -1e30f;
    #pragma unroll
    for (int i = 0; i < 32; ++i) mx = fmaxf(mx, vals[i]);
    mx = fmaxf(mx, __shfl_xor(mx, 1, 64));
    mx = fmaxf(mx, __shfl_xor(mx, 2, 64));
    float sum = 0.0f;
    #pragma unroll
    for (int i = 0; i < 32; ++i) { vals[i] = expf(vals[i] - mx); sum += vals[i]; }
    sum += __shfl_xor(sum, 1, 64);
    sum += __shfl_xor(sum, 2, 64);
    const float inv = 1.0f / sum;
    #pragma unroll
    for (int jj = 0; jj < 4; ++jj) {
      const int tcp = quarter * 4 + jj;
      s16x8 pk;
      #pragma unroll
      for (int i = 0; i < 8; ++i) pk[i] = f2bf(vals[jj * 8 + i] * inv);
      *(s16x8*)(SC + q * 512 + ((tcp ^ (q & 15)) << 4)) = pk;
    }
  }
  __syncthreads();

  // --- PV ---
  f32x4 oacc[2][2] = {};
  #pragma unroll
  for (int kt = 0; kt < 4; ++kt) {
    s16x8 pa[2], vb[2];
    #pragma unroll
    for (int m = 0; m < 2; ++m) {
      const int q = wr * 32 + m * 16 + rl;
      const int tcp = kt * 4 + kcg;
      pa[m] = *(const s16x8*)(SC + q * 512 + ((tcp ^ (q & 15)) << 4));
    }
    #pragma unroll
    for (int n = 0; n < 2; ++n) {
      const int d = wc * 32 + n * 16 + rl;
      const int tc = kt * 4 + kcg;
      vb[n] = *(const s16x8*)(VT + d * 256 + ((tc ^ (d & 15)) << 4));
    }
    #pragma unroll
    for (int m = 0; m < 2; ++m)
      #pragma unroll
      for (int n = 0; n < 2; ++n)
        oacc[m][n] = __builtin_amdgcn_mfma_f32_16x16x32_bf16(pa[m], vb[n], oacc[m][n], 0, 0, 0);
  }
  // epilogue: res[b,q,s,h*64+d]
  #pragma unroll
  for (int m = 0; m < 2; ++m)
    #pragma unroll
    for (int n = 0; n < 2; ++n)
      #pragma unroll
      for (int r = 0; r < 4; ++r) {
        const int q = wr * 32 + m * 16 + (lane >> 4) * 4 + r;
        const int d = wc * 32 + n * 16 + rl;
        res[(((size_t)b * Q_ + q) * S_ + s) * H_ + h * HD_ + d] =
            __float2bfloat16(oacc[m][n][r]);
      }
}

// ---------------------------------------------------------------------------
// Row LayerNorm over H=768, templated in/out dtypes.
// ---------------------------------------------------------------------------
template<bool ADD, typename IT, typename OT>
__global__ __launch_bounds__(256) void ln_kernel(
    const IT* __restrict__ X, const IT* __restrict__ X2,
    const float* __restrict__ g, const float* __restrict__ bta,
    OT* __restrict__ Y)
{
  const size_t row = blockIdx.x;
  const int tid = threadIdx.x;
  float v[3];
  #pragma unroll
  for (int i = 0; i < 3; ++i) {
    int c = tid + i * 256;
    v[i] = ldT(X, row * H_ + c);
    if (ADD) v[i] += ldT(X2, row * H_ + c);
  }
  float sum = v[0] + v[1] + v[2];
  #pragma unroll
  for (int off = 32; off > 0; off >>= 1) sum += __shfl_down(sum, off, 64);
  __shared__ float red[8];
  const int w = tid >> 6;
  if ((tid & 63) == 0) red[w] = sum;
  __syncthreads();
  const float mean = (red[0] + red[1] + red[2] + red[3]) * (1.0f / 768.0f);
  float vs = 0.0f;
  #pragma unroll
  for (int i = 0; i < 3; ++i) { v[i] -= mean; vs += v[i] * v[i]; }
  #pragma unroll
  for (int off = 32; off > 0; off >>= 1) vs += __shfl_down(vs, off, 64);
  if ((tid & 63) == 0) red[4 + w] = vs;
  __syncthreads();
  const float rstd = rsqrtf((red[4] + red[5] + red[6] + red[7]) * (1.0f / 768.0f) + 1e-12f);
  #pragma unroll
  for (int i = 0; i < 3; ++i) {
    int c = tid + i * 256;
    stT(Y, row * H_ + c, v[i] * rstd * g[c] + bta[c]);
  }
}

// ---------------------------------------------------------------------------
extern "C" void kernel_launch(void* const* d_in, const int* in_sizes, int n_in,
                              void* d_out, int out_size, void* d_ws, size_t ws_size,
                              hipStream_t stream) {
  const float* q    = (const float*)d_in[0];
  const float* k    = (const float*)d_in[1];
  const int*   mask = (const int*)d_in[2];
  const float* Wq   = (const float*)d_in[3];
  const float* Wkv  = (const float*)d_in[4];
  const float* Wo   = (const float*)d_in[5];
  const float* bo   = (const float*)d_in[6];
  const float* ln1g = (const float*)d_in[7];
  const float* ln1b = (const float*)d_in[8];
  const float* W1   = (const float*)d_in[9];
  const float* b1   = (const float*)d_in[10];
  const float* W2   = (const float*)d_in[11];
  const float* b2   = (const float*)d_in[12];
  const float* ln2g = (const float*)d_in[13];
  const float* ln2b = (const float*)d_in[14];
  float* out = (float*)d_out;

  const int MROWS = B_ * Q_ * S_;           // 24576
  const int KVROWS = B_ * S_ * T_;          // 49152

  // workspace layout (bytes), lifetime-based reuse:
  char* ws = (char*)d_ws;
  __hip_bfloat16* kbf  = (__hip_bfloat16*)ws;                        // 75.5MB
  __hip_bfloat16* kvp  = (__hip_bfloat16*)(ws + 75497472);           // 75.5MB
  __hip_bfloat16* ffn1 = (__hip_bfloat16*)ws;                        // 151MB (reuse)
  __hip_bfloat16* ares = (__hip_bfloat16*)(ws + 150994944);          // 37.7MB
  __hip_bfloat16* ffn2 = ares;                                       // reuse
  __hip_bfloat16* aln  = (__hip_bfloat16*)(ws + 188743680);          // 37.7MB
  __hip_bfloat16* qp   = (__hip_bfloat16*)(ws + 226492416);          // 0.8MB (bf16 now)
  __hip_bfloat16* WkvT = (__hip_bfloat16*)(ws + 228065280);
  __hip_bfloat16* WoT  = (__hip_bfloat16*)(ws + 229244928);
  __hip_bfloat16* W1T  = (__hip_bfloat16*)(ws + 230424576);
  __hip_bfloat16* W2T  = (__hip_bfloat16*)(ws + 235143168);

  dim3 blk(256);

  // weight prep
  transpose_cast<<<dim3(24, 24), blk, 0, stream>>>(Wkv, WkvT, H_, H_);
  transpose_cast<<<dim3(24, 24), blk, 0, stream>>>(Wo, WoT, H_, H_);
  transpose_cast<<<dim3(96, 24), blk, 0, stream>>>(W1, W1T, H_, FF_);
  transpose_cast<<<dim3(24, 96), blk, 0, stream>>>(W2, W2T, FF_, H_);
  cast_f32_bf16<<<dim3((KVROWS * H_ / 4 + 255) / 256), blk, 0, stream>>>(
      k, kbf, (size_t)KVROWS * H_ / 4);

  // 1. q projection (fp32 in, bf16 out)
  gemm64<__hip_bfloat16><<<dim3(H_ / 64, 512 / 64), blk, 0, stream>>>(
      q, Wq, qp, 512, H_, H_);
  // 2. kv projection -> bf16
  gemm_mfma<__hip_bfloat16, false, false>
      <<<dim3((KVROWS / 128) * (H_ / 128)), blk, 0, stream>>>(
      kbf, WkvT, nullptr, kvp, H_, H_, H_ / 128);
  // 3. MFMA attention -> ares (bf16)
  attn_mfma<<<dim3(S_, NH_, B_), blk, 0, stream>>>(qp, kvp, mask, ares);
  // 4. ares @ Wo + bo -> d_out (f32 pre-LN scratch)
  gemm_mfma<float, true, false>
      <<<dim3((MROWS / 128) * (H_ / 128)), blk, 0, stream>>>(
      ares, WoT, bo, out, H_, H_, H_ / 128);
  // 5. LN1: d_out -> aln (bf16)
  ln_kernel<false, float, __hip_bfloat16><<<MROWS, blk, 0, stream>>>(
      out, nullptr, ln1g, ln1b, aln);
  // 6. aln @ W1 + b1, gelu -> ffn1 (bf16)
  gemm_mfma<__hip_bfloat16, true, true>
      <<<dim3((MROWS / 128) * (FF_ / 128)), blk, 0, stream>>>(
      aln, W1T, b1, ffn1, FF_, H_, FF_ / 128);
  // 7. ffn1 @ W2 + b2 -> ffn2 (bf16)
  gemm_mfma<__hip_bfloat16, true, false>
      <<<dim3((MROWS / 128) * (H_ / 128)), blk, 0, stream>>>(
      ffn1, W2T, b2, ffn2, H_, FF_, H_ / 128);
  // 8. LN2: out = LN(aln + ffn2)
  ln_kernel<true, __hip_bfloat16, float><<<MROWS, blk, 0, stream>>>(
      aln, ffn2, ln2g, ln2b, out);
}

// Round 5
// 658.587 us; speedup vs baseline: 9.6470x; 1.0388x over previous
//
#include <hip/hip_runtime.h>
#include <hip/hip_bf16.h>
#include <math.h>

// Problem constants
#define B_ 8
#define Q_ 64
#define S_ 48
#define T_ 128
#define H_ 768
#define NH_ 12
#define HD_ 64
#define FF_ 3072

typedef float f32x4 __attribute__((ext_vector_type(4)));
typedef short s16x8 __attribute__((ext_vector_type(8)));
typedef short s16x4 __attribute__((ext_vector_type(4)));

__device__ __forceinline__ float ldT(const float* p, size_t i) { return p[i]; }
__device__ __forceinline__ float ldT(const __hip_bfloat16* p, size_t i) { return __bfloat162float(p[i]); }
__device__ __forceinline__ void stT(float* p, size_t i, float v) { p[i] = v; }
__device__ __forceinline__ void stT(__hip_bfloat16* p, size_t i, float v) { p[i] = __float2bfloat16(v); }

__device__ __forceinline__ short f2bf(float f) {
  __hip_bfloat16 h = __float2bfloat16(f);
  return *reinterpret_cast<short*>(&h);
}

__device__ __forceinline__ float gelu_f(float x) {
  return 0.5f * x * (1.0f + erff(x * 0.70710678118654752f));
}

// async global->LDS, 16B per lane
__device__ __forceinline__ void gld_lds16(const void* g, void* l) {
  __builtin_amdgcn_global_load_lds(
      (const __attribute__((address_space(1))) void*)g,
      (__attribute__((address_space(3))) void*)l, 16, 0, 0);
}

// ---------------------------------------------------------------------------
// MFMA bf16 GEMM: C[M,N] = act(A[M,K] @ BT[N,K]^T + bias)
// 128x128 tile, BK=32, 256 threads (4 waves, 2x2), each wave 64x64 out.
// 3-deep LDS pipeline with counted vmcnt (T3/T4): stage tile t+2 while
// computing tile t; wait vmcnt(4) = only tile t's 4 loads must have landed.
// Single raw s_barrier per K-step (no full drain).
// Requires M%128==0, N%128==0, K%32==0, grid = (M/128)*(N/128), %8==0.
// ---------------------------------------------------------------------------
__device__ __forceinline__ int swz_off(int row, int kc) {
  // byte offset of 16B chunk (row, k-chunk kc) in a [128][32] bf16 tile,
  // slot swizzled: slot = kc ^ ((row>>1)&3)  (involution)
  return row * 64 + ((kc ^ ((row >> 1) & 3)) << 4);
}

template<typename OT, bool BIAS, bool GELU>
__global__ __launch_bounds__(256) void gemm_mfma(
    const __hip_bfloat16* __restrict__ A,   // [M,K]
    const __hip_bfloat16* __restrict__ BT,  // [N,K]
    const float* __restrict__ bias, OT* __restrict__ C,
    int N, int K, int nbx)
{
  __shared__ char sm[3][16384];   // per buf: A at 0 (8KB), B at 8192 (8KB)

  // XCD-aware chunked swizzle (grid %8 == 0 for all our launches)
  int wg = blockIdx.x;
  const int q8 = gridDim.x >> 3;
  wg = (wg & 7) * q8 + (wg >> 3);
  const int bm = wg / nbx;
  const int bn = wg % nbx;
  const int m0 = bm * 128, n0 = bn * 128;

  const int tid = threadIdx.x;
  const int lane = tid & 63;
  const int wid = tid >> 6;
  const int wr = wid >> 1, wc = wid & 1;

  const int nt = K >> 5;

  auto stage = [&](int buf, int kt) {
    const int k0 = kt << 5;
    const __hip_bfloat16* Ab = A + (size_t)m0 * K + k0;
    const __hip_bfloat16* Bb = BT + (size_t)n0 * K + k0;
    char* smA = sm[buf];
    char* smB = sm[buf] + 8192;
    #pragma unroll
    for (int r = 0; r < 2; ++r) {
      const int c = tid + r * 256;           // chunk 0..511
      const int row = c >> 2, slot = c & 3;
      const int kc = slot ^ ((row >> 1) & 3); // pre-swizzled source
      gld_lds16(Ab + (size_t)row * K + kc * 8, smA + c * 16);
      gld_lds16(Bb + (size_t)row * K + kc * 8, smB + c * 16);
    }
  };

  f32x4 acc[4][4] = {};
  stage(0, 0);
  if (nt > 1) stage(1, 1);

  int cur = 0;
  for (int kt = 0; kt < nt; ++kt) {
    // tile kt's 4 loads (per thread) are the oldest; tile kt+1's 4 may fly.
    if (kt + 1 < nt) asm volatile("s_waitcnt vmcnt(4)" ::: "memory");
    else             asm volatile("s_waitcnt vmcnt(0)" ::: "memory");
    __builtin_amdgcn_s_barrier();
    asm volatile("" ::: "memory");

    const char* smA = sm[cur];
    const char* smB = sm[cur] + 8192;
    const int kc = lane >> 4, rl = lane & 15;
    s16x8 af[4], bf[4];
    #pragma unroll
    for (int m = 0; m < 4; ++m)
      af[m] = *(const s16x8*)(smA + swz_off(wr * 64 + m * 16 + rl, kc));
    #pragma unroll
    for (int n = 0; n < 4; ++n)
      bf[n] = *(const s16x8*)(smB + swz_off(wc * 64 + n * 16 + rl, kc));

    // stage tile kt+2 into the buffer freed after iteration kt-1
    int nb = cur + 2; if (nb >= 3) nb -= 3;
    if (kt + 2 < nt) stage(nb, kt + 2);

    #pragma unroll
    for (int m = 0; m < 4; ++m)
      #pragma unroll
      for (int n = 0; n < 4; ++n)
        acc[m][n] = __builtin_amdgcn_mfma_f32_16x16x32_bf16(af[m], bf[n], acc[m][n], 0, 0, 0);

    ++cur; if (cur == 3) cur = 0;
  }

  // epilogue: C/D layout col=lane&15, row=(lane>>4)*4+r  [m89-verified]
  // n innermost so each 128B output line is written by consecutive stores.
  const int colb = n0 + wc * 64 + (lane & 15);
  const int rowb = m0 + wr * 64 + (lane >> 4) * 4;
  float bv[4];
  #pragma unroll
  for (int n = 0; n < 4; ++n) bv[n] = BIAS ? bias[colb + n * 16] : 0.0f;
  #pragma unroll
  for (int m = 0; m < 4; ++m) {
    #pragma unroll
    for (int r = 0; r < 4; ++r) {
      const int row = rowb + m * 16 + r;
      #pragma unroll
      for (int n = 0; n < 4; ++n) {
        float v = acc[m][n][r] + bv[n];
        if (GELU) v = gelu_f(v);
        stT(C, (size_t)row * N + colb + n * 16, v);
      }
    }
  }
}

// ---------------------------------------------------------------------------
// fp32 LDS-tiled GEMM (q-projection only), templated output
// ---------------------------------------------------------------------------
template<typename OT>
__global__ __launch_bounds__(256) void gemm64(
    const float* __restrict__ A, const float* __restrict__ W,
    OT* __restrict__ C, int M, int N, int K)
{
  __shared__ float As[16][65];
  __shared__ float Ws[16][65];
  const int tid = threadIdx.x;
  const int m0 = blockIdx.y * 64;
  const int n0 = blockIdx.x * 64;
  const int tx = (tid & 15) * 4;
  const int ty = (tid >> 4) * 4;
  float acc[4][4] = {};

  for (int k0 = 0; k0 < K; k0 += 16) {
    #pragma unroll
    for (int r = 0; r < 4; ++r) {
      int idx = tid + r * 256;
      int mm = idx >> 4, kk = idx & 15;
      As[kk][mm] = A[(size_t)(m0 + mm) * K + (k0 + kk)];
    }
    #pragma unroll
    for (int r = 0; r < 4; ++r) {
      int idx = tid + r * 256;
      int kk = idx >> 6, nn = idx & 63;
      Ws[kk][nn] = W[(size_t)(k0 + kk) * N + (n0 + nn)];
    }
    __syncthreads();
    #pragma unroll
    for (int kk = 0; kk < 16; ++kk) {
      float a[4], b[4];
      #pragma unroll
      for (int i = 0; i < 4; ++i) a[i] = As[kk][ty + i];
      #pragma unroll
      for (int j = 0; j < 4; ++j) b[j] = Ws[kk][tx + j];
      #pragma unroll
      for (int i = 0; i < 4; ++i)
        #pragma unroll
        for (int j = 0; j < 4; ++j) acc[i][j] += a[i] * b[j];
    }
    __syncthreads();
  }
  #pragma unroll
  for (int i = 0; i < 4; ++i)
    #pragma unroll
    for (int j = 0; j < 4; ++j)
      stT(C, (size_t)(m0 + ty + i) * N + (n0 + tx + j), acc[i][j]);
}

// ---------------------------------------------------------------------------
// weight transpose-cast: W[K,N] f32 -> WT[N,K] bf16
// ---------------------------------------------------------------------------
__global__ __launch_bounds__(256) void transpose_cast(
    const float* __restrict__ W, __hip_bfloat16* __restrict__ WT, int K, int N)
{
  __shared__ float t[32][33];
  const int n0 = blockIdx.x * 32, k0 = blockIdx.y * 32;
  const int x = threadIdx.x & 31, y4 = (threadIdx.x >> 5) * 4;
  #pragma unroll
  for (int i = 0; i < 4; ++i)
    t[y4 + i][x] = W[(size_t)(k0 + y4 + i) * N + n0 + x];
  __syncthreads();
  #pragma unroll
  for (int i = 0; i < 4; ++i)
    WT[(size_t)(n0 + y4 + i) * K + k0 + x] = __float2bfloat16(t[x][y4 + i]);
}

// elementwise cast f32 -> bf16, 4 elems/thread
__global__ __launch_bounds__(256) void cast_f32_bf16(
    const float* __restrict__ x, __hip_bfloat16* __restrict__ y, size_t n4)
{
  const size_t i = (size_t)blockIdx.x * 256 + threadIdx.x;
  if (i >= n4) return;
  const float4 v = ((const float4*)x)[i];
  __hip_bfloat16 o[4] = { __float2bfloat16(v.x), __float2bfloat16(v.y),
                          __float2bfloat16(v.z), __float2bfloat16(v.w) };
  *(ushort4*)(y + i * 4) = *(ushort4*)o;
}

// ---------------------------------------------------------------------------
// MFMA attention. Block = (s, h, b). 256 threads = 4 waves (2x2).
// QK^T: 64q x 128t over d=64; softmax over t; PV: 64q x 64d over t=128.
// LDS: Ks 16K | VT 16K | SC 32K (Qs overlay / Sc f32 / Pb bf16) | mv 512B
// All tiles chunk-XOR swizzled for bank-conflict-free ds_read_b128.
// ---------------------------------------------------------------------------
__global__ __launch_bounds__(256) void attn_mfma(
    const __hip_bfloat16* __restrict__ qp,   // [B*Q][H] bf16
    const __hip_bfloat16* __restrict__ kvp,  // [B*S*T][H] bf16
    const int* __restrict__ mask,
    __hip_bfloat16* __restrict__ res)        // [B,Q,S,H] bf16
{
  const int s = blockIdx.x, h = blockIdx.y, b = blockIdx.z;
  __shared__ __align__(16) char lds[66048];
  char* Ks = lds;                  // [128t][64d]: chunk(t,kc8)@ t*128+((kc8^(t&7))<<4)
  char* VT = lds + 16384;          // [64d][128t]: chunk(d,tc)@ d*256+((tc^(d&15))<<4)
  char* SC = lds + 32768;          // Qs overlay; Sc f32 (q,tc32)@ q*512+((tc32^(q&31))<<4)
                                   // Pb bf16 (q,tcp)@ q*512+((tcp^(q&15))<<4)
  float* mv = (float*)(lds + 65536);

  const int tid = threadIdx.x;
  const int lane = tid & 63;
  const int wid = tid >> 6;
  const int wr = wid >> 1, wc = wid & 1;
  const int kcg = lane >> 4, rl = lane & 15;

  if (tid < 128) mv[tid] = (float)mask[((size_t)b * S_ + s) * T_ + tid] * -10000.0f;

  // --- stage Q via global_load_lds (linear LDS dest, pre-swizzled source) ---
  {
    const __hip_bfloat16* qb = qp + ((size_t)b * Q_) * H_ + h * HD_;
    #pragma unroll
    for (int r = 0; r < 2; ++r) {
      const int c = tid + r * 256;            // 512 chunks: Qs[64q][8 chunks]
      const int qq = c >> 3, sc = c & 7;
      const int kc8 = sc ^ (qq & 7);
      gld_lds16(qb + (size_t)qq * H_ + kc8 * 8, SC + c * 16);
    }
  }
  // --- stage K/V via registers: Ks (swizzled b128) + VT (transposed b64) ---
  {
    const int kc8 = tid & 7, tg = tid >> 3;   // tg 0..31, t0 = tg*4
    const int t0 = tg * 4;
    const __hip_bfloat16* kb = kvp + (((size_t)b * S_ + s) * T_) * H_ + h * HD_ + kc8 * 8;
    s16x8 r0 = *(const s16x8*)(kb + (size_t)(t0 + 0) * H_);
    s16x8 r1 = *(const s16x8*)(kb + (size_t)(t0 + 1) * H_);
    s16x8 r2 = *(const s16x8*)(kb + (size_t)(t0 + 2) * H_);
    s16x8 r3 = *(const s16x8*)(kb + (size_t)(t0 + 3) * H_);
    *(s16x8*)(Ks + (t0 + 0) * 128 + ((kc8 ^ ((t0 + 0) & 7)) << 4)) = r0;
    *(s16x8*)(Ks + (t0 + 1) * 128 + ((kc8 ^ ((t0 + 1) & 7)) << 4)) = r1;
    *(s16x8*)(Ks + (t0 + 2) * 128 + ((kc8 ^ ((t0 + 2) & 7)) << 4)) = r2;
    *(s16x8*)(Ks + (t0 + 3) * 128 + ((kc8 ^ ((t0 + 3) & 7)) << 4)) = r3;
    const int tc = tg >> 1;
    const int toff = (tg & 1) * 8;
    #pragma unroll
    for (int j = 0; j < 8; ++j) {
      s16x4 v4 = { r0[j], r1[j], r2[j], r3[j] };
      const int d = kc8 * 8 + j;
      *(s16x4*)(VT + d * 256 + ((tc ^ (d & 15)) << 4) + toff) = v4;
    }
  }
  __syncthreads();

  // --- QK^T ---
  f32x4 acc[2][4] = {};
  {
    s16x8 af[2][2], bf[2][4];
    #pragma unroll
    for (int kk = 0; kk < 2; ++kk) {
      #pragma unroll
      for (int m = 0; m < 2; ++m) {
        const int q = wr * 32 + m * 16 + rl;
        const int kc8 = kk * 4 + kcg;
        af[kk][m] = *(const s16x8*)(SC + q * 128 + ((kc8 ^ (q & 7)) << 4));
      }
      #pragma unroll
      for (int n = 0; n < 4; ++n) {
        const int t = wc * 64 + n * 16 + rl;
        const int kc8 = kk * 4 + kcg;
        bf[kk][n] = *(const s16x8*)(Ks + t * 128 + ((kc8 ^ (t & 7)) << 4));
      }
    }
    #pragma unroll
    for (int kk = 0; kk < 2; ++kk)
      #pragma unroll
      for (int m = 0; m < 2; ++m)
        #pragma unroll
        for (int n = 0; n < 4; ++n)
          acc[m][n] = __builtin_amdgcn_mfma_f32_16x16x32_bf16(af[kk][m], bf[kk][n], acc[m][n], 0, 0, 0);
  }
  __syncthreads();   // all Qs frag reads done before Sc overwrites the region

  // epilogue: Sc = acc*SCALE + mask
  #pragma unroll
  for (int m = 0; m < 2; ++m)
    #pragma unroll
    for (int n = 0; n < 4; ++n)
      #pragma unroll
      for (int r = 0; r < 4; ++r) {
        const int q = wr * 32 + m * 16 + (lane >> 4) * 4 + r;
        const int t = wc * 64 + n * 16 + rl;
        const int tc32 = t >> 2;
        *(float*)(SC + q * 512 + ((tc32 ^ (q & 31)) << 4) + (t & 3) * 4) =
            acc[m][n][r] * 0.125f + mv[t];
      }
  __syncthreads();

  // --- softmax: 4 lanes per q-row, 32 t each ---
  {
    const int q = tid >> 2, quarter = tid & 3;
    float vals[32];
    #pragma unroll
    for (int j = 0; j < 8; ++j) {
      const int tc32 = quarter * 8 + j;
      const f32x4 c = *(const f32x4*)(SC + q * 512 + ((tc32 ^ (q & 31)) << 4));
      vals[j * 4 + 0] = c[0]; vals[j * 4 + 1] = c[1];
      vals[j * 4 + 2] = c[2]; vals[j * 4 + 3] = c[3];
    }
    float mx = -1e30f;
    #pragma unroll
    for (int i = 0; i < 32; ++i) mx = fmaxf(mx, vals[i]);
    mx = fmaxf(mx, __shfl_xor(mx, 1, 64));
    mx = fmaxf(mx, __shfl_xor(mx, 2, 64));
    float sum = 0.0f;
    #pragma unroll
    for (int i = 0; i < 32; ++i) { vals[i] = expf(vals[i] - mx); sum += vals[i]; }
    sum += __shfl_xor(sum, 1, 64);
    sum += __shfl_xor(sum, 2, 64);
    const float inv = 1.0f / sum;
    #pragma unroll
    for (int jj = 0; jj < 4; ++jj) {
      const int tcp = quarter * 4 + jj;
      s16x8 pk;
      #pragma unroll
      for (int i = 0; i < 8; ++i) pk[i] = f2bf(vals[jj * 8 + i] * inv);
      *(s16x8*)(SC + q * 512 + ((tcp ^ (q & 15)) << 4)) = pk;
    }
  }
  __syncthreads();

  // --- PV ---
  f32x4 oacc[2][2] = {};
  #pragma unroll
  for (int kt = 0; kt < 4; ++kt) {
    s16x8 pa[2], vb[2];
    #pragma unroll
    for (int m = 0; m < 2; ++m) {
      const int q = wr * 32 + m * 16 + rl;
      const int tcp = kt * 4 + kcg;
      pa[m] = *(const s16x8*)(SC + q * 512 + ((tcp ^ (q & 15)) << 4));
    }
    #pragma unroll
    for (int n = 0; n < 2; ++n) {
      const int d = wc * 32 + n * 16 + rl;
      const int tc = kt * 4 + kcg;
      vb[n] = *(const s16x8*)(VT + d * 256 + ((tc ^ (d & 15)) << 4));
    }
    #pragma unroll
    for (int m = 0; m < 2; ++m)
      #pragma unroll
      for (int n = 0; n < 2; ++n)
        oacc[m][n] = __builtin_amdgcn_mfma_f32_16x16x32_bf16(pa[m], vb[n], oacc[m][n], 0, 0, 0);
  }
  // epilogue: res[b,q,s,h*64+d]
  #pragma unroll
  for (int m = 0; m < 2; ++m)
    #pragma unroll
    for (int n = 0; n < 2; ++n)
      #pragma unroll
      for (int r = 0; r < 4; ++r) {
        const int q = wr * 32 + m * 16 + (lane >> 4) * 4 + r;
        const int d = wc * 32 + n * 16 + rl;
        res[(((size_t)b * Q_ + q) * S_ + s) * H_ + h * HD_ + d] =
            __float2bfloat16(oacc[m][n][r]);
      }
}

// ---------------------------------------------------------------------------
// Row LayerNorm over H=768, templated in/out dtypes.
// ---------------------------------------------------------------------------
template<bool ADD, typename IT, typename OT>
__global__ __launch_bounds__(256) void ln_kernel(
    const IT* __restrict__ X, const IT* __restrict__ X2,
    const float* __restrict__ g, const float* __restrict__ bta,
    OT* __restrict__ Y)
{
  const size_t row = blockIdx.x;
  const int tid = threadIdx.x;
  float v[3];
  #pragma unroll
  for (int i = 0; i < 3; ++i) {
    int c = tid + i * 256;
    v[i] = ldT(X, row * H_ + c);
    if (ADD) v[i] += ldT(X2, row * H_ + c);
  }
  float sum = v[0] + v[1] + v[2];
  #pragma unroll
  for (int off = 32; off > 0; off >>= 1) sum += __shfl_down(sum, off, 64);
  __shared__ float red[8];
  const int w = tid >> 6;
  if ((tid & 63) == 0) red[w] = sum;
  __syncthreads();
  const float mean = (red[0] + red[1] + red[2] + red[3]) * (1.0f / 768.0f);
  float vs = 0.0f;
  #pragma unroll
  for (int i = 0; i < 3; ++i) { v[i] -= mean; vs += v[i] * v[i]; }
  #pragma unroll
  for (int off = 32; off > 0; off >>= 1) vs += __shfl_down(vs, off, 64);
  if ((tid & 63) == 0) red[4 + w] = vs;
  __syncthreads();
  const float rstd = rsqrtf((red[4] + red[5] + red[6] + red[7]) * (1.0f / 768.0f) + 1e-12f);
  #pragma unroll
  for (int i = 0; i < 3; ++i) {
    int c = tid + i * 256;
    stT(Y, row * H_ + c, v[i] * rstd * g[c] + bta[c]);
  }
}

// ---------------------------------------------------------------------------
extern "C" void kernel_launch(void* const* d_in, const int* in_sizes, int n_in,
                              void* d_out, int out_size, void* d_ws, size_t ws_size,
                              hipStream_t stream) {
  const float* q    = (const float*)d_in[0];
  const float* k    = (const float*)d_in[1];
  const int*   mask = (const int*)d_in[2];
  const float* Wq   = (const float*)d_in[3];
  const float* Wkv  = (const float*)d_in[4];
  const float* Wo   = (const float*)d_in[5];
  const float* bo   = (const float*)d_in[6];
  const float* ln1g = (const float*)d_in[7];
  const float* ln1b = (const float*)d_in[8];
  const float* W1   = (const float*)d_in[9];
  const float* b1   = (const float*)d_in[10];
  const float* W2   = (const float*)d_in[11];
  const float* b2   = (const float*)d_in[12];
  const float* ln2g = (const float*)d_in[13];
  const float* ln2b = (const float*)d_in[14];
  float* out = (float*)d_out;

  const int MROWS = B_ * Q_ * S_;           // 24576
  const int KVROWS = B_ * S_ * T_;          // 49152

  // workspace layout (bytes), lifetime-based reuse:
  char* ws = (char*)d_ws;
  __hip_bfloat16* kbf  = (__hip_bfloat16*)ws;                        // 75.5MB
  __hip_bfloat16* kvp  = (__hip_bfloat16*)(ws + 75497472);           // 75.5MB
  __hip_bfloat16* ffn1 = (__hip_bfloat16*)ws;                        // 151MB (reuse)
  __hip_bfloat16* ares = (__hip_bfloat16*)(ws + 150994944);          // 37.7MB
  __hip_bfloat16* ffn2 = ares;                                       // reuse
  __hip_bfloat16* aln  = (__hip_bfloat16*)(ws + 188743680);          // 37.7MB
  __hip_bfloat16* qp   = (__hip_bfloat16*)(ws + 226492416);          // 0.8MB (bf16)
  __hip_bfloat16* WkvT = (__hip_bfloat16*)(ws + 228065280);
  __hip_bfloat16* WoT  = (__hip_bfloat16*)(ws + 229244928);
  __hip_bfloat16* W1T  = (__hip_bfloat16*)(ws + 230424576);
  __hip_bfloat16* W2T  = (__hip_bfloat16*)(ws + 235143168);

  dim3 blk(256);

  // weight prep
  transpose_cast<<<dim3(24, 24), blk, 0, stream>>>(Wkv, WkvT, H_, H_);
  transpose_cast<<<dim3(24, 24), blk, 0, stream>>>(Wo, WoT, H_, H_);
  transpose_cast<<<dim3(96, 24), blk, 0, stream>>>(W1, W1T, H_, FF_);
  transpose_cast<<<dim3(24, 96), blk, 0, stream>>>(W2, W2T, FF_, H_);
  cast_f32_bf16<<<dim3((KVROWS * H_ / 4 + 255) / 256), blk, 0, stream>>>(
      k, kbf, (size_t)KVROWS * H_ / 4);

  // 1. q projection (fp32 in, bf16 out)
  gemm64<__hip_bfloat16><<<dim3(H_ / 64, 512 / 64), blk, 0, stream>>>(
      q, Wq, qp, 512, H_, H_);
  // 2. kv projection -> bf16
  gemm_mfma<__hip_bfloat16, false, false>
      <<<dim3((KVROWS / 128) * (H_ / 128)), blk, 0, stream>>>(
      kbf, WkvT, nullptr, kvp, H_, H_, H_ / 128);
  // 3. MFMA attention -> ares (bf16)
  attn_mfma<<<dim3(S_, NH_, B_), blk, 0, stream>>>(qp, kvp, mask, ares);
  // 4. ares @ Wo + bo -> d_out (f32 pre-LN scratch)
  gemm_mfma<float, true, false>
      <<<dim3((MROWS / 128) * (H_ / 128)), blk, 0, stream>>>(
      ares, WoT, bo, out, H_, H_, H_ / 128);
  // 5. LN1: d_out -> aln (bf16)
  ln_kernel<false, float, __hip_bfloat16><<<MROWS, blk, 0, stream>>>(
      out, nullptr, ln1g, ln1b, aln);
  // 6. aln @ W1 + b1, gelu -> ffn1 (bf16)
  gemm_mfma<__hip_bfloat16, true, true>
      <<<dim3((MROWS / 128) * (FF_ / 128)), blk, 0, stream>>>(
      aln, W1T, b1, ffn1, FF_, H_, FF_ / 128);
  // 7. ffn1 @ W2 + b2 -> ffn2 (bf16)
  gemm_mfma<__hip_bfloat16, true, false>
      <<<dim3((MROWS / 128) * (H_ / 128)), blk, 0, stream>>>(
      ffn1, W2T, b2, ffn2, H_, FF_, H_ / 128);
  // 8. LN2: out = LN(aln + ffn2)
  ln_kernel<true, __hip_bfloat16, float><<<MROWS, blk, 0, stream>>>(
      aln, ffn2, ln2g, ln2b, out);
}